// Round 2
// baseline (322.111 us; speedup 1.0000x reference)
//
#include <hip/hip_runtime.h>
#include <stdint.h>

// Problem constants (from reference setup_inputs)
#define M_TOK 8192
#define N_OUT 4096
#define K_IN  4096

// GEMM tiling: 256x256 tile, BK=64, double-buffered LDS (128 KiB), 8 waves 2x4
#define BM 256
#define BN 256
#define BK 64
#define NT (K_IN / BK)            // 64 K-tiles
#define BUF 32768                 // shorts per buffer (64 KiB): A[2][256][32], B[2][256][32]
#define SEC 8192                  // shorts per k-slice section (256 rows x 32)

typedef float floatx4 __attribute__((ext_vector_type(4)));
typedef __bf16 bf16x8 __attribute__((ext_vector_type(8)));
typedef unsigned short ushort8_t __attribute__((ext_vector_type(8)));

#define MFMA16 __builtin_amdgcn_mfma_f32_16x16x32_bf16

// ---------- helpers ----------

__device__ __forceinline__ unsigned short f32_to_bf16_rne(float f) {
    union { float f; unsigned int u; } v; v.f = f;
    unsigned int u = v.u;
    u += 0x7FFFu + ((u >> 16) & 1u);   // round-to-nearest-even; inputs have no NaN
    return (unsigned short)(u >> 16);
}

// async global->LDS, 16 bytes per lane. LDS side is wave-uniform base + lane*16.
__device__ __forceinline__ void async_copy16(const void* g, void* l) {
    __builtin_amdgcn_global_load_lds(
        (__attribute__((address_space(1))) void*)(g),
        (__attribute__((address_space(3))) void*)(l),
        16, 0, 0);
}

// ---------- pre-pass: fp32 -> bf16 ----------

__global__ void cvt_f32_bf16_kernel(const float* __restrict__ in,
                                    unsigned short* __restrict__ out, int n8) {
    int i = blockIdx.x * 256 + threadIdx.x;
    if (i >= n8) return;
    const float4* p = (const float4*)in + (size_t)i * 2;
    float4 a = p[0];
    float4 b = p[1];
    ushort8_t o;
    o[0] = f32_to_bf16_rne(a.x); o[1] = f32_to_bf16_rne(a.y);
    o[2] = f32_to_bf16_rne(a.z); o[3] = f32_to_bf16_rne(a.w);
    o[4] = f32_to_bf16_rne(b.x); o[5] = f32_to_bf16_rne(b.y);
    o[6] = f32_to_bf16_rne(b.z); o[7] = f32_to_bf16_rne(b.w);
    *((ushort8_t*)out + i) = o;
}

// ---------- pre-pass: int32 (int8-valued) -> bf16 (exact) ----------

__global__ void cvt_i32_bf16_kernel(const int* __restrict__ in,
                                    unsigned short* __restrict__ out, int n8) {
    int i = blockIdx.x * 256 + threadIdx.x;
    if (i >= n8) return;
    const int4* p = (const int4*)in + (size_t)i * 2;
    int4 a = p[0];
    int4 b = p[1];
    ushort8_t o;
    o[0] = f32_to_bf16_rne((float)a.x); o[1] = f32_to_bf16_rne((float)a.y);
    o[2] = f32_to_bf16_rne((float)a.z); o[3] = f32_to_bf16_rne((float)a.w);
    o[4] = f32_to_bf16_rne((float)b.x); o[5] = f32_to_bf16_rne((float)b.y);
    o[6] = f32_to_bf16_rne((float)b.z); o[7] = f32_to_bf16_rne((float)b.w);
    *((ushort8_t*)out + i) = o;
}

// ---------- GEMM: C[m][n] = sum_k A[m][k]*B[n][k]; C = acc*scale[n]+bias[n] ----------
// m201-style 4-phase schedule per BK=64 K-tile. 512 threads = 8 waves (2Mx4N),
// per-wave output 128x64 = acc[8][4] of 16x16 frags, 2 k-slices per tile.
//
// LDS buffer layout (k-slice-major so each staged half-tile is CONTIGUOUS):
//   A_s0 [0,SEC) | A_s1 [SEC,2*SEC) | B_s0 [2S,3S) | B_s1 [3S,4S), each 256x32.
// Per phase: {ds_read 4-8 b128 | stage ONE half-tile (2 global_load_lds) ->
//   barrier -> lgkmcnt(0) -> setprio(1) -> 16 MFMA -> setprio(0) -> barrier}.
// Counted waits (exact outstanding-count simulation, 2 loads/half-tile):
//   W_mid (end P2): outstanding = k1(t)[4] + k0(t+1)[4] -> vmcnt(4) drains k1(t).
//   W_bnd (end P4): outstanding = k0(t+1)[4] + k1(t+1)[4] -> vmcnt(4) drains k0(t+1).
// Never vmcnt(0) in the main loop (only at the t=NT-1 tail).
//
// Swizzle (T2, both sides): within a section, slot v of row r holds global
// 8-short chunk (v ^ (r&3)). Read side: v = q ^ (lane&3) (row&3 == lane&3 for
// all frags). Enumerated bank pattern: 8 lanes per 4-bank group per
// ds_read_b128 -> conflict-free.

__global__ __launch_bounds__(512, 2)
void gemm_bf16_kernel(const unsigned short* __restrict__ A,
                      const unsigned short* __restrict__ B,
                      const float* __restrict__ scales,
                      const float* __restrict__ bias,
                      float* __restrict__ C) {
    __shared__ __align__(16) unsigned short lds[2 * BUF];   // 128 KiB

    const int tid = threadIdx.x;

    // T1: bijective XCD swizzle (nwg = 512, divisible by 8), bn-fastest.
    const int nwg = (M_TOK / BM) * (N_OUT / BN);   // 32*16 = 512
    const int cpx = nwg / 8;                        // 64
    const int wg  = (blockIdx.x % 8) * cpx + blockIdx.x / 8;
    const int bn  = wg & 15;                        // N_OUT/BN = 16
    const int bm  = wg >> 4;                        // 0..31

    const int lane = tid & 63;
    const int wave = tid >> 6;          // 0..7
    const int wm   = wave >> 2;         // 0..1 -> rows wm*128
    const int wn   = wave & 3;          // 0..3 -> cols wn*64

    // ---- staging addressing (loop-invariant) ----
    // Half-tile = 256 rows x 32 k of one matrix = 16 KiB = 2 issues.
    // Issue i: linear chunk c = i*512+tid -> row = i*128 + (tid>>2), slot = tid&3.
    // Inverse swizzle on the GLOBAL source: chunk = slot ^ (row&3).
    const int srow = tid >> 2;                      // 0..127
    const int scb  = (tid & 3) ^ (srow & 3);
    const unsigned short* aP = A + (size_t)(bm * BM + srow) * K_IN + scb * 8;
    const unsigned short* bP = B + (size_t)(bn * BN + srow) * K_IN + scb * 8;

    auto stA = [&](int tt, int s) {
        unsigned short* d = &lds[(tt & 1) * BUF + s * SEC + tid * 8];
        const unsigned short* g = aP + tt * BK + s * 32;
        async_copy16(g, d);
        async_copy16(g + (size_t)128 * K_IN, d + 4096);
    };
    auto stB = [&](int tt, int s) {
        unsigned short* d = &lds[(tt & 1) * BUF + 2 * SEC + s * SEC + tid * 8];
        const unsigned short* g = bP + tt * BK + s * 32;
        async_copy16(g, d);
        async_copy16(g + (size_t)128 * K_IN, d + 4096);
    };

    // ---- fragment read addressing (loop-invariant) ----
    // Frag row = (wm*128 or wn*64) + fr*16 + (lane&15); k = q*8+j within slice.
    // row&3 == lane&3 -> swizzle term per-lane constant.
    const int r16 = lane & 15;
    const int q   = lane >> 4;                      // 0..3
    const int sw  = (q ^ (lane & 3)) * 8;           // shorts
    const int aOff = (wm * 128 + r16) * 32 + sw;            // within A_s section
    const int bOff = 2 * SEC + (wn * 64 + r16) * 32 + sw;   // within buffer

    floatx4 acc[8][4] = {};

    // ---- prologue: stage tile 0 (k0 then k1), wait only for k0 ----
    stA(0, 0); stB(0, 0); stA(0, 1); stB(0, 1);
    asm volatile("s_waitcnt vmcnt(4)" ::: "memory");   // k0(0) landed
    __builtin_amdgcn_s_barrier();
    asm volatile("" ::: "memory");

#pragma unroll 1
    for (int t = 0; t < NT; ++t) {
        const unsigned short* Lb = &lds[(t & 1) * BUF];
        const unsigned short* ar = Lb + aOff;
        const unsigned short* br = Lb + bOff;
        const bool pf = (t + 1 < NT);
        bf16x8 af[4], bf[4];

        // ---- P1: s0, frag rows 0-3, cols 0-3 (8 ds_read) ----
#pragma unroll
        for (int i = 0; i < 4; ++i) af[i] = *(const bf16x8*)(ar + i * 512);
#pragma unroll
        for (int j = 0; j < 4; ++j) bf[j] = *(const bf16x8*)(br + j * 512);
        if (pf) stA(t + 1, 0);
        __builtin_amdgcn_s_barrier();
        asm volatile("s_waitcnt lgkmcnt(0)" ::: "memory");
        __builtin_amdgcn_s_setprio(1);
#pragma unroll
        for (int i = 0; i < 4; ++i)
#pragma unroll
            for (int j = 0; j < 4; ++j)
                acc[i][j] = MFMA16(af[i], bf[j], acc[i][j], 0, 0, 0);
        __builtin_amdgcn_s_setprio(0);
        __builtin_amdgcn_s_barrier();

        // ---- P2: s0, frag rows 4-7 (4 ds_read; B reused in regs) ----
#pragma unroll
        for (int i = 0; i < 4; ++i) af[i] = *(const bf16x8*)(ar + (4 + i) * 512);
        if (pf) stB(t + 1, 0);
        __builtin_amdgcn_s_barrier();
        asm volatile("s_waitcnt lgkmcnt(0)" ::: "memory");
        __builtin_amdgcn_s_setprio(1);
#pragma unroll
        for (int i = 0; i < 4; ++i)
#pragma unroll
            for (int j = 0; j < 4; ++j)
                acc[4 + i][j] = MFMA16(af[i], bf[j], acc[4 + i][j], 0, 0, 0);
        __builtin_amdgcn_s_setprio(0);
        // W_mid: drain this tile's k1 halves (counted)
        if (pf) asm volatile("s_waitcnt vmcnt(4)" ::: "memory");
        else    asm volatile("s_waitcnt vmcnt(0)" ::: "memory");
        __builtin_amdgcn_s_barrier();
        asm volatile("" ::: "memory");

        // ---- P3: s1, frag rows 0-3, cols 0-3 (8 ds_read) ----
#pragma unroll
        for (int i = 0; i < 4; ++i) af[i] = *(const bf16x8*)(ar + SEC + i * 512);
#pragma unroll
        for (int j = 0; j < 4; ++j) bf[j] = *(const bf16x8*)(br + SEC + j * 512);
        if (pf) stA(t + 1, 1);
        __builtin_amdgcn_s_barrier();
        asm volatile("s_waitcnt lgkmcnt(0)" ::: "memory");
        __builtin_amdgcn_s_setprio(1);
#pragma unroll
        for (int i = 0; i < 4; ++i)
#pragma unroll
            for (int j = 0; j < 4; ++j)
                acc[i][j] = MFMA16(af[i], bf[j], acc[i][j], 0, 0, 0);
        __builtin_amdgcn_s_setprio(0);
        __builtin_amdgcn_s_barrier();

        // ---- P4: s1, frag rows 4-7 (4 ds_read; B reused) ----
#pragma unroll
        for (int i = 0; i < 4; ++i) af[i] = *(const bf16x8*)(ar + SEC + (4 + i) * 512);
        if (pf) stB(t + 1, 1);
        __builtin_amdgcn_s_barrier();
        asm volatile("s_waitcnt lgkmcnt(0)" ::: "memory");
        __builtin_amdgcn_s_setprio(1);
#pragma unroll
        for (int i = 0; i < 4; ++i)
#pragma unroll
            for (int j = 0; j < 4; ++j)
                acc[4 + i][j] = MFMA16(af[i], bf[j], acc[4 + i][j], 0, 0, 0);
        __builtin_amdgcn_s_setprio(0);
        // W_bnd: drain next tile's k0 halves (counted); skip at final tile
        if (pf) {
            asm volatile("s_waitcnt vmcnt(4)" ::: "memory");
            __builtin_amdgcn_s_barrier();
            asm volatile("" ::: "memory");
        }
    }

    // ---- epilogue: C/D layout col = lane&15, row = (lane>>4)*4 + reg ----
    const int row0 = bm * BM + wm * 128 + q * 4;
    const int col0 = bn * BN + wn * 64 + r16;
#pragma unroll
    for (int fc = 0; fc < 4; ++fc) {
        const int n  = col0 + fc * 16;
        const float sc = scales[n];
        const float bi = bias[n];
#pragma unroll
        for (int fr = 0; fr < 8; ++fr) {
            const int m = row0 + fr * 16;
#pragma unroll
            for (int r = 0; r < 4; ++r)
                C[(size_t)(m + r) * N_OUT + n] = acc[fr][fc][r] * sc + bi;
        }
    }
}

// ---------- launch ----------

extern "C" void kernel_launch(void* const* d_in, const int* in_sizes, int n_in,
                              void* d_out, int out_size, void* d_ws, size_t ws_size,
                              hipStream_t stream) {
    const float* x      = (const float*)d_in[0];
    const int*   wq     = (const int*)d_in[1];
    const float* scales = (const float*)d_in[2];
    const float* bias   = (const float*)d_in[3];
    float*       out    = (float*)d_out;

    unsigned short* xb = (unsigned short*)d_ws;                       // 64 MiB
    unsigned short* wb = xb + (size_t)M_TOK * K_IN;                   // 32 MiB
    // ws needed: (8192*4096 + 4096*4096) * 2 = 96 MiB

    const int nx8 = (M_TOK * K_IN) / 8;   // 4194304
    const int nw8 = (N_OUT * K_IN) / 8;   // 2097152
    cvt_f32_bf16_kernel<<<nx8 / 256, 256, 0, stream>>>(x, xb, nx8);
    cvt_i32_bf16_kernel<<<nw8 / 256, 256, 0, stream>>>(wq, wb, nw8);

    const int grid = (M_TOK / BM) * (N_OUT / BN);   // 32 * 16 = 512
    gemm_bf16_kernel<<<grid, 512, 0, stream>>>(xb, wb, scales, bias, out);
}

// Round 3
// 311.656 us; speedup vs baseline: 1.0335x; 1.0335x over previous
//
#include <hip/hip_runtime.h>
#include <stdint.h>

// Problem constants (from reference setup_inputs)
#define M_TOK 8192
#define N_OUT 4096
#define K_IN  4096

// GEMM tiling: 256x256 tile, BK=64, double-buffered LDS (128 KiB), 8 waves 2x4
#define BM 256
#define BN 256
#define BK 64
#define NT (K_IN / BK)            // 64 K-tiles
#define BUF 32768                 // shorts per buffer (64 KiB)
#define SEC 8192                  // shorts per k-slice section (256 rows x 32)

typedef float floatx4 __attribute__((ext_vector_type(4)));
typedef __bf16 bf16x8 __attribute__((ext_vector_type(8)));
typedef unsigned short ushort8_t __attribute__((ext_vector_type(8)));

#define MFMA16 __builtin_amdgcn_mfma_f32_16x16x32_bf16

// ---------- helpers ----------

__device__ __forceinline__ unsigned short f32_to_bf16_rne(float f) {
    union { float f; unsigned int u; } v; v.f = f;
    unsigned int u = v.u;
    u += 0x7FFFu + ((u >> 16) & 1u);   // round-to-nearest-even; inputs have no NaN
    return (unsigned short)(u >> 16);
}

// async global->LDS, 16 bytes per lane. LDS side is wave-uniform base + lane*16.
__device__ __forceinline__ void async_copy16(const void* g, void* l) {
    __builtin_amdgcn_global_load_lds(
        (__attribute__((address_space(1))) void*)(g),
        (__attribute__((address_space(3))) void*)(l),
        16, 0, 0);
}

// ---------- pre-pass: fp32 -> bf16 ----------

__global__ void cvt_f32_bf16_kernel(const float* __restrict__ in,
                                    unsigned short* __restrict__ out, int n8) {
    int i = blockIdx.x * 256 + threadIdx.x;
    if (i >= n8) return;
    const float4* p = (const float4*)in + (size_t)i * 2;
    float4 a = p[0];
    float4 b = p[1];
    ushort8_t o;
    o[0] = f32_to_bf16_rne(a.x); o[1] = f32_to_bf16_rne(a.y);
    o[2] = f32_to_bf16_rne(a.z); o[3] = f32_to_bf16_rne(a.w);
    o[4] = f32_to_bf16_rne(b.x); o[5] = f32_to_bf16_rne(b.y);
    o[6] = f32_to_bf16_rne(b.z); o[7] = f32_to_bf16_rne(b.w);
    *((ushort8_t*)out + i) = o;
}

// ---------- pre-pass: int32 (int8-valued) -> bf16 (exact) ----------

__global__ void cvt_i32_bf16_kernel(const int* __restrict__ in,
                                    unsigned short* __restrict__ out, int n8) {
    int i = blockIdx.x * 256 + threadIdx.x;
    if (i >= n8) return;
    const int4* p = (const int4*)in + (size_t)i * 2;
    int4 a = p[0];
    int4 b = p[1];
    ushort8_t o;
    o[0] = f32_to_bf16_rne((float)a.x); o[1] = f32_to_bf16_rne((float)a.y);
    o[2] = f32_to_bf16_rne((float)a.z); o[3] = f32_to_bf16_rne((float)a.w);
    o[4] = f32_to_bf16_rne((float)b.x); o[5] = f32_to_bf16_rne((float)b.y);
    o[6] = f32_to_bf16_rne((float)b.z); o[7] = f32_to_bf16_rne((float)b.w);
    *((ushort8_t*)out + i) = o;
}

// ---------- GEMM: C[m][n] = sum_k A[m][k]*B[n][k]; C = acc*scale[n]+bias[n] ----------
// 4-phase schedule per BK=64 K-tile (m201-style). 512 threads = 8 waves (2Mx4N),
// per-wave output 128x64 = acc[8][4] of 16x16 frags, 2 k-slices per tile.
//
// LDS buffer: k-slice-major sections A_s0 | A_s1 | B_s0 | B_s1, each 16 KiB.
// PAIR-ROW swizzle (fixes R2's 2.5e7 bank conflicts): within a section, pair
// p (128 B, bank-aligned) holds global rows {2p, 2p+1} of one k-slice; chunk
// (p, c) holds (row = 2p + (cg>>2), kchunk = cg&3), cg = c ^ (p&7).
// Read (R, q): p = R>>1, c = ((R&1)*4 + q) ^ ((R>>1)&7) -> per-lane constant.
// Enumerated: each 16-lane group of a ds_read_b128 hits each 4-bank slot
// exactly 2x (the free 2-way case) -- the same geometry that measured 0
// conflicts in the 128-byte-row kernel. Inverse swizzle applied on the
// per-lane GLOBAL source; global_load_lds LDS dest stays linear (both-sides
// rule).
//
// Per phase: {ds_read 4-8 b128 | stage ONE half-tile (2 global_load_lds) ->
//   barrier -> lgkmcnt(0) -> setprio(1) -> 16 MFMA -> setprio(0) -> barrier}.
// Counted waits (2 loads/half-tile; each awaited load issued 2-3 phases prior):
//   W_mid (end P2): outstanding = k1(t)[4] + k0(t+1)[4] -> vmcnt(4) drains k1(t).
//   W_bnd (end P4): outstanding = k0(t+1)[4] + k1(t+1)[4] -> vmcnt(4) drains k0(t+1).
// Never vmcnt(0) in the main loop (only at the t=NT-1 tail).

__global__ __launch_bounds__(512, 2)
void gemm_bf16_kernel(const unsigned short* __restrict__ A,
                      const unsigned short* __restrict__ B,
                      const float* __restrict__ scales,
                      const float* __restrict__ bias,
                      float* __restrict__ C) {
    __shared__ __align__(16) unsigned short lds[2 * BUF];   // 128 KiB

    const int tid = threadIdx.x;

    // T1: bijective XCD swizzle (nwg = 512, divisible by 8), bn-fastest.
    const int nwg = (M_TOK / BM) * (N_OUT / BN);   // 32*16 = 512
    const int cpx = nwg / 8;                        // 64
    const int wg  = (blockIdx.x % 8) * cpx + blockIdx.x / 8;
    const int bn  = wg & 15;                        // N_OUT/BN = 16
    const int bm  = wg >> 4;                        // 0..31

    const int lane = tid & 63;
    const int wave = tid >> 6;          // 0..7
    const int wm   = wave >> 2;         // 0..1 -> rows wm*128
    const int wn   = wave & 3;          // 0..3 -> cols wn*64

    // ---- staging addressing (loop-invariant) ----
    // One issue = 512 lanes x 16 B = 8 KiB = 64 pair-rows = 128 global rows of
    // one k-slice. Lane t -> pair p = i*64 + (t>>3), chunk c = t&7;
    // cg = c ^ (p&7) = (t&7) ^ ((t>>3)&7) (i*64 is 0 mod 8).
    const int t8 = tid >> 3;                        // 0..63
    const int cg = (tid & 7) ^ (t8 & 7);            // unswizzled chunk in pair
    const int grow0 = 2 * t8 + (cg >> 2);           // row within 128-row issue
    const int gcol0 = (cg & 3) * 8;                 // shorts within k-slice
    const unsigned short* aP = A + (size_t)(bm * BM + grow0) * K_IN + gcol0;
    const unsigned short* bP = B + (size_t)(bn * BN + grow0) * K_IN + gcol0;

    auto stA = [&](int tt, int s) {
        unsigned short* d = &lds[(tt & 1) * BUF + s * SEC + tid * 8];
        const unsigned short* g = aP + tt * BK + s * 32;
        async_copy16(g, d);
        async_copy16(g + (size_t)128 * K_IN, d + 4096);
    };
    auto stB = [&](int tt, int s) {
        unsigned short* d = &lds[(tt & 1) * BUF + 2 * SEC + s * SEC + tid * 8];
        const unsigned short* g = bP + tt * BK + s * 32;
        async_copy16(g, d);
        async_copy16(g + (size_t)128 * K_IN, d + 4096);
    };

    // ---- fragment read addressing (loop-invariant) ----
    // Frag row R = (wm*128|wn*64) + fr*16 + r16; pair p = R>>1; p&7 = (r16>>1)&7
    // (fr*16/2 = fr*8 == 0 mod 8). c = ((r16&1)*4 + q) ^ ((r16>>1)&7).
    const int r16 = lane & 15;
    const int q   = lane >> 4;                      // 0..3
    const int cr  = (((r16 & 1) << 2) + q) ^ ((r16 >> 1) & 7);
    const int aOff = (wm * 64 + (r16 >> 1)) * 64 + cr * 8;
    const int bOff = 2 * SEC + (wn * 32 + (r16 >> 1)) * 64 + cr * 8;

    floatx4 acc[8][4] = {};

    // ---- prologue: stage tile 0 (k0 then k1), wait only for k0 ----
    stA(0, 0); stB(0, 0); stA(0, 1); stB(0, 1);
    asm volatile("s_waitcnt vmcnt(4)" ::: "memory");   // k0(0) landed
    __builtin_amdgcn_s_barrier();
    asm volatile("" ::: "memory");

#pragma unroll 1
    for (int t = 0; t < NT; ++t) {
        const unsigned short* Lb = &lds[(t & 1) * BUF];
        const unsigned short* ar = Lb + aOff;
        const unsigned short* br = Lb + bOff;
        const bool pf = (t + 1 < NT);
        bf16x8 af[4], bf[4];

        // ---- P1: s0, frag rows 0-3, cols 0-3 (8 ds_read) ----
#pragma unroll
        for (int i = 0; i < 4; ++i) af[i] = *(const bf16x8*)(ar + i * 512);
#pragma unroll
        for (int j = 0; j < 4; ++j) bf[j] = *(const bf16x8*)(br + j * 512);
        if (pf) stA(t + 1, 0);
        __builtin_amdgcn_s_barrier();
        asm volatile("s_waitcnt lgkmcnt(0)" ::: "memory");
        __builtin_amdgcn_s_setprio(1);
#pragma unroll
        for (int i = 0; i < 4; ++i)
#pragma unroll
            for (int j = 0; j < 4; ++j)
                acc[i][j] = MFMA16(af[i], bf[j], acc[i][j], 0, 0, 0);
        __builtin_amdgcn_s_setprio(0);
        __builtin_amdgcn_s_barrier();

        // ---- P2: s0, frag rows 4-7 (4 ds_read; B reused in regs) ----
#pragma unroll
        for (int i = 0; i < 4; ++i) af[i] = *(const bf16x8*)(ar + (4 + i) * 512);
        if (pf) stB(t + 1, 0);
        __builtin_amdgcn_s_barrier();
        asm volatile("s_waitcnt lgkmcnt(0)" ::: "memory");
        __builtin_amdgcn_s_setprio(1);
#pragma unroll
        for (int i = 0; i < 4; ++i)
#pragma unroll
            for (int j = 0; j < 4; ++j)
                acc[4 + i][j] = MFMA16(af[i], bf[j], acc[4 + i][j], 0, 0, 0);
        __builtin_amdgcn_s_setprio(0);
        // W_mid: drain this tile's k1 halves (counted)
        if (pf) asm volatile("s_waitcnt vmcnt(4)" ::: "memory");
        else    asm volatile("s_waitcnt vmcnt(0)" ::: "memory");
        __builtin_amdgcn_s_barrier();
        asm volatile("" ::: "memory");

        // ---- P3: s1, frag rows 0-3, cols 0-3 (8 ds_read) ----
#pragma unroll
        for (int i = 0; i < 4; ++i) af[i] = *(const bf16x8*)(ar + SEC + i * 512);
#pragma unroll
        for (int j = 0; j < 4; ++j) bf[j] = *(const bf16x8*)(br + SEC + j * 512);
        if (pf) stA(t + 1, 1);
        __builtin_amdgcn_s_barrier();
        asm volatile("s_waitcnt lgkmcnt(0)" ::: "memory");
        __builtin_amdgcn_s_setprio(1);
#pragma unroll
        for (int i = 0; i < 4; ++i)
#pragma unroll
            for (int j = 0; j < 4; ++j)
                acc[i][j] = MFMA16(af[i], bf[j], acc[i][j], 0, 0, 0);
        __builtin_amdgcn_s_setprio(0);
        __builtin_amdgcn_s_barrier();

        // ---- P4: s1, frag rows 4-7 (4 ds_read; B reused) ----
#pragma unroll
        for (int i = 0; i < 4; ++i) af[i] = *(const bf16x8*)(ar + SEC + (4 + i) * 512);
        if (pf) stB(t + 1, 1);
        __builtin_amdgcn_s_barrier();
        asm volatile("s_waitcnt lgkmcnt(0)" ::: "memory");
        __builtin_amdgcn_s_setprio(1);
#pragma unroll
        for (int i = 0; i < 4; ++i)
#pragma unroll
            for (int j = 0; j < 4; ++j)
                acc[4 + i][j] = MFMA16(af[i], bf[j], acc[4 + i][j], 0, 0, 0);
        __builtin_amdgcn_s_setprio(0);
        // W_bnd: drain next tile's k0 halves (counted); skip at final tile
        if (pf) {
            asm volatile("s_waitcnt vmcnt(4)" ::: "memory");
            __builtin_amdgcn_s_barrier();
            asm volatile("" ::: "memory");
        }
    }

    // ---- epilogue: C/D layout col = lane&15, row = (lane>>4)*4 + reg ----
    const int row0 = bm * BM + wm * 128 + q * 4;
    const int col0 = bn * BN + wn * 64 + r16;
#pragma unroll
    for (int fc = 0; fc < 4; ++fc) {
        const int n  = col0 + fc * 16;
        const float sc = scales[n];
        const float bi = bias[n];
#pragma unroll
        for (int fr = 0; fr < 8; ++fr) {
            const int m = row0 + fr * 16;
#pragma unroll
            for (int r = 0; r < 4; ++r)
                C[(size_t)(m + r) * N_OUT + n] = acc[fr][fc][r] * sc + bi;
        }
    }
}

// ---------- launch ----------

extern "C" void kernel_launch(void* const* d_in, const int* in_sizes, int n_in,
                              void* d_out, int out_size, void* d_ws, size_t ws_size,
                              hipStream_t stream) {
    const float* x      = (const float*)d_in[0];
    const int*   wq     = (const int*)d_in[1];
    const float* scales = (const float*)d_in[2];
    const float* bias   = (const float*)d_in[3];
    float*       out    = (float*)d_out;

    unsigned short* xb = (unsigned short*)d_ws;                       // 64 MiB
    unsigned short* wb = xb + (size_t)M_TOK * K_IN;                   // 32 MiB
    // ws needed: (8192*4096 + 4096*4096) * 2 = 96 MiB

    const int nx8 = (M_TOK * K_IN) / 8;   // 4194304
    const int nw8 = (N_OUT * K_IN) / 8;   // 2097152
    cvt_f32_bf16_kernel<<<nx8 / 256, 256, 0, stream>>>(x, xb, nx8);
    cvt_i32_bf16_kernel<<<nw8 / 256, 256, 0, stream>>>(wq, wb, nw8);

    const int grid = (M_TOK / BM) * (N_OUT / BN);   // 32 * 16 = 512
    gemm_bf16_kernel<<<grid, 512, 0, stream>>>(xb, wb, scales, bias, out);
}

// Round 4
// 297.797 us; speedup vs baseline: 1.0816x; 1.0465x over previous
//
#include <hip/hip_runtime.h>
#include <stdint.h>

// Problem constants (from reference setup_inputs)
#define M_TOK 8192
#define N_OUT 4096
#define K_IN  4096

// GEMM tiling: 256x256 tile, BK=64, double-buffered LDS (128 KiB), 8 waves 2x4
#define BM 256
#define BN 256
#define BK 64
#define NT (K_IN / BK)            // 64 K-tiles
#define BUF 32768                 // shorts per buffer (64 KiB)
#define SEC 8192                  // shorts per k-slice section (256 rows x 32)

typedef float floatx4 __attribute__((ext_vector_type(4)));
typedef __bf16 bf16x8 __attribute__((ext_vector_type(8)));
typedef unsigned short ushort8_t __attribute__((ext_vector_type(8)));

#define MFMA16 __builtin_amdgcn_mfma_f32_16x16x32_bf16

// ---------- helpers ----------

__device__ __forceinline__ unsigned short f32_to_bf16_rne(float f) {
    union { float f; unsigned int u; } v; v.f = f;
    unsigned int u = v.u;
    u += 0x7FFFu + ((u >> 16) & 1u);   // round-to-nearest-even; inputs have no NaN
    return (unsigned short)(u >> 16);
}

// async global->LDS, 16 bytes per lane. LDS side is wave-uniform base + lane*16.
__device__ __forceinline__ void async_copy16(const void* g, void* l) {
    __builtin_amdgcn_global_load_lds(
        (__attribute__((address_space(1))) void*)(g),
        (__attribute__((address_space(3))) void*)(l),
        16, 0, 0);
}

// ---------- pre-pass: fp32 -> bf16 ----------

__global__ void cvt_f32_bf16_kernel(const float* __restrict__ in,
                                    unsigned short* __restrict__ out, int n8) {
    int i = blockIdx.x * 256 + threadIdx.x;
    if (i >= n8) return;
    const float4* p = (const float4*)in + (size_t)i * 2;
    float4 a = p[0];
    float4 b = p[1];
    ushort8_t o;
    o[0] = f32_to_bf16_rne(a.x); o[1] = f32_to_bf16_rne(a.y);
    o[2] = f32_to_bf16_rne(a.z); o[3] = f32_to_bf16_rne(a.w);
    o[4] = f32_to_bf16_rne(b.x); o[5] = f32_to_bf16_rne(b.y);
    o[6] = f32_to_bf16_rne(b.z); o[7] = f32_to_bf16_rne(b.w);
    *((ushort8_t*)out + i) = o;
}

// ---------- pre-pass: int32 (int8-valued) -> bf16 (exact) ----------

__global__ void cvt_i32_bf16_kernel(const int* __restrict__ in,
                                    unsigned short* __restrict__ out, int n8) {
    int i = blockIdx.x * 256 + threadIdx.x;
    if (i >= n8) return;
    const int4* p = (const int4*)in + (size_t)i * 2;
    int4 a = p[0];
    int4 b = p[1];
    ushort8_t o;
    o[0] = f32_to_bf16_rne((float)a.x); o[1] = f32_to_bf16_rne((float)a.y);
    o[2] = f32_to_bf16_rne((float)a.z); o[3] = f32_to_bf16_rne((float)a.w);
    o[4] = f32_to_bf16_rne((float)b.x); o[5] = f32_to_bf16_rne((float)b.y);
    o[6] = f32_to_bf16_rne((float)b.z); o[7] = f32_to_bf16_rne((float)b.w);
    *((ushort8_t*)out + i) = o;
}

// ---------- GEMM: C[m][n] = sum_k A[m][k]*B[n][k]; C = acc*scale[n]+bias[n] ----------
// 4-phase schedule per BK=64 K-tile with REGISTER-LEVEL FRAGMENT PIPELINING:
// each phase issues the NEXT phase's ds_reads into a ping-pong register set,
// waits a COUNTED lgkmcnt (drains prev phase's reads, leaves this phase's in
// flight), then runs 16 MFMA -> DS pipe and matrix pipe overlap instead of
// serializing behind per-phase barriers (R3 measured MfmaUtil 45% = exact
// serial sum of DS ~2100cyc + MFMA ~2480cyc per tile per CU).
//
// Barriers: 2 per tile, only at the cross-wave visibility points (each paired
// with the counted vmcnt(4) that drains the wave's own stage loads for the
// section about to be read). Hazard matrix verified: every LDS read of a
// region is lgkm-drained before its consuming MFMA, which precedes the
// barrier that precedes any wave's overwriting stage issue.
//
// LDS: k-slice-major sections A_s0 | A_s1 | B_s0 | B_s1, 16 KiB each.
// PAIR-ROW swizzle (R3-verified: 0 bank conflicts): pair p (128 B) holds
// global rows {2p,2p+1}; chunk (p,c) holds (row = 2p+(cg>>2), kchunk = cg&3),
// cg = c ^ (p&7); inverse on the per-lane GLOBAL source, linear LDS dest.
//
// lgkm counts per phase (DS ops return in order per wave):
//   before MFMA1: outstanding = P1's 4 reads          -> lgkmcnt(4)
//   before MFMA2: outstanding = P1's 4 + P2's 8       -> lgkmcnt(8)
//   before MFMA3: outstanding = P2's(drained)+P3's 4  -> lgkmcnt(4)
//   before MFMA4: outstanding = P3's 4 + P4's 8       -> lgkmcnt(8)
// vmcnt: P2 drains k1(t) [vmcnt(4)], P4 drains k0(t+1) [vmcnt(4)]; never 0
// in steady state.

__global__ __launch_bounds__(512, 2)
void gemm_bf16_kernel(const unsigned short* __restrict__ A,
                      const unsigned short* __restrict__ B,
                      const float* __restrict__ scales,
                      const float* __restrict__ bias,
                      float* __restrict__ C) {
    __shared__ __align__(16) unsigned short lds[2 * BUF];   // 128 KiB

    const int tid = threadIdx.x;

    // T1: bijective XCD swizzle (nwg = 512, divisible by 8), bn-fastest.
    const int nwg = (M_TOK / BM) * (N_OUT / BN);   // 32*16 = 512
    const int cpx = nwg / 8;                        // 64
    const int wg  = (blockIdx.x % 8) * cpx + blockIdx.x / 8;
    const int bn  = wg & 15;                        // N_OUT/BN = 16
    const int bm  = wg >> 4;                        // 0..31

    const int lane = tid & 63;
    const int wave = tid >> 6;          // 0..7
    const int wm   = wave >> 2;         // 0..1 -> rows wm*128
    const int wn   = wave & 3;          // 0..3 -> cols wn*64

    // ---- staging addressing (loop-invariant) ----
    // Lane t -> pair p = i*64 + (t>>3), chunk c = t&7; cg = (t&7) ^ ((t>>3)&7).
    const int t8 = tid >> 3;                        // 0..63
    const int cg = (tid & 7) ^ (t8 & 7);            // unswizzled chunk in pair
    const int grow0 = 2 * t8 + (cg >> 2);           // row within 128-row issue
    const int gcol0 = (cg & 3) * 8;                 // shorts within k-slice
    const unsigned short* aP = A + (size_t)(bm * BM + grow0) * K_IN + gcol0;
    const unsigned short* bP = B + (size_t)(bn * BN + grow0) * K_IN + gcol0;

    auto stA = [&](int tt, int s) {
        unsigned short* d = &lds[(tt & 1) * BUF + s * SEC + tid * 8];
        const unsigned short* g = aP + tt * BK + s * 32;
        async_copy16(g, d);
        async_copy16(g + (size_t)128 * K_IN, d + 4096);
    };
    auto stB = [&](int tt, int s) {
        unsigned short* d = &lds[(tt & 1) * BUF + 2 * SEC + s * SEC + tid * 8];
        const unsigned short* g = bP + tt * BK + s * 32;
        async_copy16(g, d);
        async_copy16(g + (size_t)128 * K_IN, d + 4096);
    };

    // ---- fragment read addressing (loop-invariant) ----
    // Frag row R: pair p = R>>1, c = ((R&1)*4 + q) ^ ((R>>1)&7).
    const int r16 = lane & 15;
    const int q   = lane >> 4;                      // 0..3
    const int cr  = (((r16 & 1) << 2) + q) ^ ((r16 >> 1) & 7);
    const int aOff = (wm * 64 + (r16 >> 1)) * 64 + cr * 8;
    const int bOff = 2 * SEC + (wn * 32 + (r16 >> 1)) * 64 + cr * 8;

    floatx4 acc[8][4] = {};
    bf16x8 afA[4], afB[4], bfA[4], bfB[4];

    // ---- prologue: stage tile 0, drain k0, read P1(0)'s fragments ----
    stA(0, 0); stB(0, 0); stA(0, 1); stB(0, 1);
    asm volatile("s_waitcnt vmcnt(4)" ::: "memory");   // k0(0) landed
    __builtin_amdgcn_s_barrier();
    asm volatile("" ::: "memory");
    {
        const unsigned short* ar = lds + aOff;
        const unsigned short* br = lds + bOff;
#pragma unroll
        for (int i = 0; i < 4; ++i) afA[i] = *(const bf16x8*)(ar + i * 512);
#pragma unroll
        for (int j = 0; j < 4; ++j) bfA[j] = *(const bf16x8*)(br + j * 512);
    }

#pragma unroll 1
    for (int t = 0; t < NT; ++t) {
        const unsigned short* ar  = lds + (t & 1) * BUF + aOff;
        const unsigned short* br  = lds + (t & 1) * BUF + bOff;
        const unsigned short* ar2 = lds + ((t + 1) & 1) * BUF + aOff;
        const unsigned short* br2 = lds + ((t + 1) & 1) * BUF + bOff;
        const bool pf = (t + 1 < NT);

        // ---- P1: MFMA(afA,bfA)->acc[0..3] | read A47s0->afB | stage A0' ----
        if (pf) stA(t + 1, 0);
#pragma unroll
        for (int i = 0; i < 4; ++i) afB[i] = *(const bf16x8*)(ar + (4 + i) * 512);
        asm volatile("s_waitcnt lgkmcnt(4)" ::: "memory");
        __builtin_amdgcn_sched_barrier(0);
        __builtin_amdgcn_s_setprio(1);
#pragma unroll
        for (int i = 0; i < 4; ++i)
#pragma unroll
            for (int j = 0; j < 4; ++j)
                acc[i][j] = MFMA16(afA[i], bfA[j], acc[i][j], 0, 0, 0);
        __builtin_amdgcn_s_setprio(0);

        // ---- P2: stage B0' | vmcnt+barrier | read A03s1->afA, Bs1->bfB |
        //          MFMA(afB,bfA)->acc[4..7] ----
        if (pf) stB(t + 1, 0);
        if (pf) asm volatile("s_waitcnt vmcnt(4)" ::: "memory");
        else    asm volatile("s_waitcnt vmcnt(0)" ::: "memory");
        __builtin_amdgcn_s_barrier();
        asm volatile("" ::: "memory");
#pragma unroll
        for (int i = 0; i < 4; ++i) afA[i] = *(const bf16x8*)(ar + SEC + i * 512);
#pragma unroll
        for (int j = 0; j < 4; ++j) bfB[j] = *(const bf16x8*)(br + SEC + j * 512);
        asm volatile("s_waitcnt lgkmcnt(8)" ::: "memory");
        __builtin_amdgcn_sched_barrier(0);
        __builtin_amdgcn_s_setprio(1);
#pragma unroll
        for (int i = 0; i < 4; ++i)
#pragma unroll
            for (int j = 0; j < 4; ++j)
                acc[4 + i][j] = MFMA16(afB[i], bfA[j], acc[4 + i][j], 0, 0, 0);
        __builtin_amdgcn_s_setprio(0);

        // ---- P3: MFMA(afA,bfB)->acc[0..3] | read A47s1->afB | stage A1' ----
        if (pf) stA(t + 1, 1);
#pragma unroll
        for (int i = 0; i < 4; ++i) afB[i] = *(const bf16x8*)(ar + SEC + (4 + i) * 512);
        asm volatile("s_waitcnt lgkmcnt(4)" ::: "memory");
        __builtin_amdgcn_sched_barrier(0);
        __builtin_amdgcn_s_setprio(1);
#pragma unroll
        for (int i = 0; i < 4; ++i)
#pragma unroll
            for (int j = 0; j < 4; ++j)
                acc[i][j] = MFMA16(afA[i], bfB[j], acc[i][j], 0, 0, 0);
        __builtin_amdgcn_s_setprio(0);

        // ---- P4: stage B1' | vmcnt+barrier | read next A03s0->afA, Bs0->bfA |
        //          MFMA(afB,bfB)->acc[4..7] ----
        if (pf) {
            stB(t + 1, 1);
            asm volatile("s_waitcnt vmcnt(4)" ::: "memory");  // k0(t+1) landed
            __builtin_amdgcn_s_barrier();
            asm volatile("" ::: "memory");
#pragma unroll
            for (int i = 0; i < 4; ++i) afA[i] = *(const bf16x8*)(ar2 + i * 512);
#pragma unroll
            for (int j = 0; j < 4; ++j) bfA[j] = *(const bf16x8*)(br2 + j * 512);
            asm volatile("s_waitcnt lgkmcnt(8)" ::: "memory");
        } else {
            asm volatile("s_waitcnt lgkmcnt(0)" ::: "memory");
        }
        __builtin_amdgcn_sched_barrier(0);
        __builtin_amdgcn_s_setprio(1);
#pragma unroll
        for (int i = 0; i < 4; ++i)
#pragma unroll
            for (int j = 0; j < 4; ++j)
                acc[4 + i][j] = MFMA16(afB[i], bfB[j], acc[4 + i][j], 0, 0, 0);
        __builtin_amdgcn_s_setprio(0);
    }

    // ---- epilogue: C/D layout col = lane&15, row = (lane>>4)*4 + reg ----
    const int row0 = bm * BM + wm * 128 + q * 4;
    const int col0 = bn * BN + wn * 64 + r16;
#pragma unroll
    for (int fc = 0; fc < 4; ++fc) {
        const int n  = col0 + fc * 16;
        const float sc = scales[n];
        const float bi = bias[n];
#pragma unroll
        for (int fr = 0; fr < 8; ++fr) {
            const int m = row0 + fr * 16;
#pragma unroll
            for (int r = 0; r < 4; ++r)
                C[(size_t)(m + r) * N_OUT + n] = acc[fr][fc][r] * sc + bi;
        }
    }
}

// ---------- launch ----------

extern "C" void kernel_launch(void* const* d_in, const int* in_sizes, int n_in,
                              void* d_out, int out_size, void* d_ws, size_t ws_size,
                              hipStream_t stream) {
    const float* x      = (const float*)d_in[0];
    const int*   wq     = (const int*)d_in[1];
    const float* scales = (const float*)d_in[2];
    const float* bias   = (const float*)d_in[3];
    float*       out    = (float*)d_out;

    unsigned short* xb = (unsigned short*)d_ws;                       // 64 MiB
    unsigned short* wb = xb + (size_t)M_TOK * K_IN;                   // 32 MiB
    // ws needed: (8192*4096 + 4096*4096) * 2 = 96 MiB

    const int nx8 = (M_TOK * K_IN) / 8;   // 4194304
    const int nw8 = (N_OUT * K_IN) / 8;   // 2097152
    cvt_f32_bf16_kernel<<<nx8 / 256, 256, 0, stream>>>(x, xb, nx8);
    cvt_i32_bf16_kernel<<<nw8 / 256, 256, 0, stream>>>(wq, wb, nw8);

    const int grid = (M_TOK / BM) * (N_OUT / BN);   // 32 * 16 = 512
    gemm_bf16_kernel<<<grid, 512, 0, stream>>>(xb, wb, scales, bias, out);
}